// Round 4
// baseline (57.132 us; speedup 1.0000x reference)
//
#include <hip/hip_runtime.h>
#include <hip/hip_bf16.h>
#include <math.h>

// Problem constants (from reference): B=2, P=10000, L=64, E=100
#define B_DIM 2
#define P_TOT 10000
#define L_DIM 64
#define E_DIM 100
#define THRESH 0.001f
#define NPIX 4                   // pixels per block (ping-pong pipelined)
#define NBLK (P_TOT / NPIX)      // 2500 blocks

// ---------------------------------------------------------------------------
// Kernel 1: fold all per-(b,e) math into 3 coefficients.
//   term(b,p,l,e) = exp2( d2*cA + sens*cS + L2F )
// coeff[e*2 + b] = {cA, cS, L2F, 0}
// ---------------------------------------------------------------------------
__global__ void axon_precompute(const float* __restrict__ stim,
                                const float* __restrict__ params,
                                float4* __restrict__ coeff) {
    int i = threadIdx.x;
    if (i >= B_DIM * E_DIM) return;
    int e = i >> 1;
    int b = i & 1;

    float freq = stim[(b * E_DIM + e) * 3 + 0];
    float amp  = stim[(b * E_DIM + e) * 3 + 1];
    float pdur = stim[(b * E_DIM + e) * 3 + 2];

    const float* pp = params + b * 12;
    float rho = pp[0], axl = pp[1];
    float a0 = pp[2], a1 = pp[3], a2 = pp[4], a3 = pp[5];
    float a5 = pp[7], a6 = pp[8], a7 = pp[9], a8 = pp[10], a9 = pp[11];

    float scaled = (a1 + a0 * pdur) * amp;
    float Fb = a2 * scaled + a3 * freq;
    if (!(scaled > 0.25f)) Fb = 0.f;   // AMP_CUTOFF
    if (!(amp > 0.f))      Fb = 0.f;   // !LIKE_JAX

    float rho2 = rho * rho;
    float Fsize = fmaxf(a5 * scaled + a6, 100.f / rho2);
    float axl2 = axl * axl;
    float Fstreak = fmaxf(a9 - a7 * powf(pdur, a8), 100.f / axl2);

    const float LOG2E = 1.4426950408889634f;
    float cA = -LOG2E / (2.f * rho2 * Fsize);
    float cS =  LOG2E / (axl2 * Fstreak);
    float L2F = (Fb > 0.f) ? log2f(Fb) : -1e30f;

    coeff[e * 2 + b] = make_float4(cA, cS, L2F, 0.f);
}

// ---------------------------------------------------------------------------
// Kernel 2: one block (256 thr = 4 waves) handles 4 pixels with ping-pong
// LDS buffers and a counted-vmcnt pipeline: while computing pixel i from
// buf[i&1], pixel i+1's loads stay in flight and pixel i+2's loads are
// issued into the just-freed buffer. vmcnt never drains to 0 in the loop,
// so every block keeps ~25 KB of HBM requests outstanding at all times.
// ---------------------------------------------------------------------------
__device__ __forceinline__ float4 lds_ld4(const float* p) {
    return *(const float4*)p;
}

template<int NE>
__device__ __forceinline__ void accum(const float* __restrict__ rowp,
                                      const float4* __restrict__ coeff,
                                      float sens, int ebase,
                                      float& s0, float& s1) {
    #pragma unroll
    for (int k4 = 0; k4 < NE / 4; ++k4) {
        float4 d2v = lds_ld4(rowp + k4 * 4);
        #pragma unroll
        for (int k = 0; k < 4; ++k) {
            int e = ebase + k4 * 4 + k;
            float d2 = (k == 0) ? d2v.x : (k == 1) ? d2v.y
                     : (k == 2) ? d2v.z : d2v.w;
            float4 c0 = coeff[e * 2 + 0];   // wave-uniform -> s_load
            float4 c1 = coeff[e * 2 + 1];
            s0 += __builtin_amdgcn_exp2f(fmaf(d2, c0.x, fmaf(sens, c0.y, c0.z)));
            s1 += __builtin_amdgcn_exp2f(fmaf(d2, c1.x, fmaf(sens, c1.y, c1.z)));
        }
    }
}

__global__ __launch_bounds__(256) void axon_main(
    const float* __restrict__ d2_el,
    const float* __restrict__ axon_contrib,
    const float4* __restrict__ coeff,
    float* __restrict__ out) {

    __shared__ float  d2s[2][L_DIM * E_DIM];   // 2 x 25.6 KB ping-pong
    __shared__ float2 part[4][L_DIM];          // 2 KB

    int tid  = threadIdx.x;
    int lane = tid & 63;
    int q    = __builtin_amdgcn_readfirstlane(tid >> 6);  // wave id (SGPR)
    int bid  = blockIdx.x;

    // ---- sens for all 4 pixels up-front, then drain so vmcnt accounting
    //      below counts only stage loads ----
    float sens[NPIX];
    #pragma unroll
    for (int i = 0; i < NPIX; ++i)
        sens[i] = axon_contrib[((size_t)(bid + NBLK * i) * L_DIM + lane) * 3 + 2];
    asm volatile("s_waitcnt vmcnt(0)" ::: "memory");

    // stage: wave q loads 1KB chunks [q*6, q*6+6); wave 3 also chunk 24.
    // per-wave in-flight count: 6 (waves 0-2) or 7 (wave 3).
    auto stage = [&](int i, int buf) {
        const float* gbase = d2_el + (size_t)(bid + NBLK * i) * (L_DIM * E_DIM);
        int c0 = q * 6;
        #pragma unroll
        for (int k = 0; k < 6; ++k) {
            int c = c0 + k;
            __builtin_amdgcn_global_load_lds(
                (const __attribute__((address_space(1))) float*)(gbase + c * 256 + lane * 4),
                (__attribute__((address_space(3))) float*)&d2s[buf][c * 256],
                16, 0, 0);
        }
        if (q == 3) {
            __builtin_amdgcn_global_load_lds(
                (const __attribute__((address_space(1))) float*)(gbase + 24 * 256 + lane * 4),
                (__attribute__((address_space(3))) float*)&d2s[buf][24 * 256],
                16, 0, 0);
        }
    };

    stage(0, 0);           // pixel 0 -> buf 0
    stage(1, 1);           // pixel 1 -> buf 1 (stays in flight during compute 0)

    // e-chunks per wave: {0..23, 24..47, 48..71, 72..99} (wave 3 gets 28)
    int ebase = q * 24;

    #pragma unroll
    for (int i = 0; i < NPIX; ++i) {
        int cur = i & 1;

        // barrier A: wait for pixel i's loads (leave pixel i+1's in flight)
        if (i < NPIX - 1) {
            if (q == 3) asm volatile("s_waitcnt vmcnt(7) lgkmcnt(0)\ns_barrier" ::: "memory");
            else        asm volatile("s_waitcnt vmcnt(6) lgkmcnt(0)\ns_barrier" ::: "memory");
        } else {
            asm volatile("s_waitcnt vmcnt(0) lgkmcnt(0)\ns_barrier" ::: "memory");
        }

        const float* rowp = &d2s[cur][lane * E_DIM + ebase];
        float s0 = 0.f, s1 = 0.f;
        if (q == 3) accum<28>(rowp, coeff, sens[i], ebase, s0, s1);
        else        accum<24>(rowp, coeff, sens[i], ebase, s0, s1);
        part[q][lane] = make_float2(s0, s1);

        // barrier B: partials visible; all waves done reading buf[cur]
        asm volatile("s_waitcnt lgkmcnt(0)\ns_barrier" ::: "memory");

        if (tid < 64) {
            float2 p0 = part[0][tid], p1 = part[1][tid];
            float2 p2 = part[2][tid], p3 = part[3][tid];
            float r0 = (p0.x + p1.x) + (p2.x + p3.x);
            float r1 = (p0.y + p1.y) + (p2.y + p3.y);
            #pragma unroll
            for (int off = 32; off; off >>= 1) {
                r0 = fmaxf(r0, __shfl_xor(r0, off, 64));
                r1 = fmaxf(r1, __shfl_xor(r1, off, 64));
            }
            if (tid == 0) {
                int p = bid + NBLK * i;
                out[p]         = (r0 > THRESH) ? r0 : 0.f;
                out[P_TOT + p] = (r1 > THRESH) ? r1 : 0.f;
            }
        }

        // refill the just-freed buffer with pixel i+2 (keeps vmcnt primed)
        if (i + 2 < NPIX) stage(i + 2, cur);
    }
}

extern "C" void kernel_launch(void* const* d_in, const int* in_sizes, int n_in,
                              void* d_out, int out_size, void* d_ws, size_t ws_size,
                              hipStream_t stream) {
    const float* stim         = (const float*)d_in[0];  // (B,E,3)
    const float* params       = (const float*)d_in[1];  // (B,12)
    const float* axon_contrib = (const float*)d_in[2];  // (P,L,3)
    const float* d2_el        = (const float*)d_in[3];  // (P,L,E)
    float* out = (float*)d_out;                         // (B,P) = 20000 floats
    float4* coeff = (float4*)d_ws;                      // 200 float4 = 3200 B

    axon_precompute<<<1, 256, 0, stream>>>(stim, params, coeff);
    axon_main<<<NBLK, 256, 0, stream>>>(d2_el, axon_contrib, coeff, out);
}

// Round 5
// 44.913 us; speedup vs baseline: 1.2721x; 1.2721x over previous
//
#include <hip/hip_runtime.h>
#include <hip/hip_bf16.h>
#include <math.h>

// Problem constants (from reference): B=2, P=10000, L=64, E=100
#define B_DIM 2
#define P_TOT 10000
#define L_DIM 64
#define E_DIM 100
#define THRESH 0.001f

// ---------------------------------------------------------------------------
// Single fused kernel: one block (256 thr = 4 waves) per pixel.
//
// Prologue: issue 25 global_load_lds (coalesced 1KB wave requests) for the
// pixel's contiguous 25.6 KB d2 block, then threads 0..199 compute the 200
// per-(b,e) coefficient triples into LDS while those loads are in flight:
//     term(b,p,l,e) = exp2( d2*cA + sens*cS + L2F )
//     cA = -log2e/(2 rho^2 Fsize), cS = log2e/(lam^2 Fstreak), L2F = log2(Fb)
// One __syncthreads() drains both (vmcnt + lgkmcnt).
//
// Compute: thread t -> row l = t&63, e-chunk by wave q = t>>6
// (chunks {24,24,24,28}, all 16B-aligned); coeff reads are uniform-address
// broadcast ds_read_b128 (conflict-free). Cross-wave combine via 2KB LDS,
// wave 0 does the 64-lane max butterfly and writes both batch outputs.
// ---------------------------------------------------------------------------
__device__ __forceinline__ float4 lds_ld4(const float* p) {
    return *(const float4*)p;
}

template<int NE>
__device__ __forceinline__ void accum(const float* __restrict__ rowp,
                                      const float4* __restrict__ scoef,
                                      float sens, int ebase,
                                      float& s0, float& s1) {
    #pragma unroll
    for (int k4 = 0; k4 < NE / 4; ++k4) {
        float4 d2v = lds_ld4(rowp + k4 * 4);
        #pragma unroll
        for (int k = 0; k < 4; ++k) {
            int e = ebase + k4 * 4 + k;
            float d2 = (k == 0) ? d2v.x : (k == 1) ? d2v.y
                     : (k == 2) ? d2v.z : d2v.w;
            float4 c0 = scoef[e * 2 + 0];   // uniform addr -> broadcast
            float4 c1 = scoef[e * 2 + 1];
            s0 += __builtin_amdgcn_exp2f(fmaf(d2, c0.x, fmaf(sens, c0.y, c0.z)));
            s1 += __builtin_amdgcn_exp2f(fmaf(d2, c1.x, fmaf(sens, c1.y, c1.z)));
        }
    }
}

__global__ __launch_bounds__(256) void axon_fused(
    const float* __restrict__ stim,
    const float* __restrict__ params,
    const float* __restrict__ axon_contrib,
    const float* __restrict__ d2_el,
    float* __restrict__ out) {

    __shared__ float  d2s[L_DIM * E_DIM];   // 25.6 KB, linear [l][e]
    __shared__ float4 scoef[E_DIM * B_DIM]; // 3.2 KB
    __shared__ float2 part[4][L_DIM];       // 2 KB

    int tid  = threadIdx.x;
    int lane = tid & 63;
    int q    = __builtin_amdgcn_readfirstlane(tid >> 6);  // wave id (SGPR)
    int p    = blockIdx.x;

    // ---- 1) issue stage loads first (don't depend on coefficients) ----
    const float* gbase = d2_el + (size_t)p * (L_DIM * E_DIM);
    for (int c = q; c < 25; c += 4) {
        __builtin_amdgcn_global_load_lds(
            (const __attribute__((address_space(1))) float*)(gbase + c * 256 + lane * 4),
            (__attribute__((address_space(3))) float*)&d2s[c * 256],
            16, 0, 0);
    }

    // sens for this thread's row
    float sens = axon_contrib[((size_t)p * L_DIM + lane) * 3 + 2];

    // ---- 2) coefficient compute, overlapped with in-flight loads ----
    if (tid < B_DIM * E_DIM) {
        int e = tid >> 1;
        int b = tid & 1;

        float freq = stim[(b * E_DIM + e) * 3 + 0];
        float amp  = stim[(b * E_DIM + e) * 3 + 1];
        float pdur = stim[(b * E_DIM + e) * 3 + 2];

        const float* pp = params + b * 12;
        float rho = pp[0], axl = pp[1];
        float a0 = pp[2], a1 = pp[3], a2 = pp[4], a3 = pp[5];
        float a5 = pp[7], a6 = pp[8], a7 = pp[9], a8 = pp[10], a9 = pp[11];

        float scaled = (a1 + a0 * pdur) * amp;
        float Fb = a2 * scaled + a3 * freq;
        if (!(scaled > 0.25f)) Fb = 0.f;   // AMP_CUTOFF
        if (!(amp > 0.f))      Fb = 0.f;   // !LIKE_JAX

        float rho2 = rho * rho;
        float Fsize = fmaxf(a5 * scaled + a6, 100.f / rho2);
        float axl2 = axl * axl;
        // pdur in (0.1, 1] -> pow via native log2/exp2
        float powv = __builtin_amdgcn_exp2f(a8 * __builtin_amdgcn_logf(pdur));
        float Fstreak = fmaxf(a9 - a7 * powv, 100.f / axl2);

        const float LOG2E = 1.4426950408889634f;
        float cA = -LOG2E / (2.f * rho2 * Fsize);
        float cS =  LOG2E / (axl2 * Fstreak);
        float L2F = (Fb > 0.f) ? __builtin_amdgcn_logf(Fb) : -1e30f;

        scoef[e * 2 + b] = make_float4(cA, cS, L2F, 0.f);
    }

    __syncthreads();   // drains vmcnt (stage) + lgkmcnt (coeff writes)

    // ---- 3) compute: row l = lane, e-chunk per wave {24,24,24,28} ----
    int ebase = q * 24;
    const float* rowp = &d2s[lane * E_DIM + ebase];

    float s0 = 0.f, s1 = 0.f;
    if (q == 3) accum<28>(rowp, (const float4*)scoef, sens, ebase, s0, s1);
    else        accum<24>(rowp, (const float4*)scoef, sens, ebase, s0, s1);
    part[q][lane] = make_float2(s0, s1);

    __syncthreads();

    // ---- 4) wave 0: combine quarters, max over l, write both batches ----
    if (tid < 64) {
        float2 p0 = part[0][tid], p1 = part[1][tid];
        float2 p2 = part[2][tid], p3 = part[3][tid];
        float r0 = (p0.x + p1.x) + (p2.x + p3.x);
        float r1 = (p0.y + p1.y) + (p2.y + p3.y);
        #pragma unroll
        for (int off = 32; off; off >>= 1) {
            r0 = fmaxf(r0, __shfl_xor(r0, off, 64));
            r1 = fmaxf(r1, __shfl_xor(r1, off, 64));
        }
        if (tid == 0) {
            out[p]         = (r0 > THRESH) ? r0 : 0.f;
            out[P_TOT + p] = (r1 > THRESH) ? r1 : 0.f;
        }
    }
}

extern "C" void kernel_launch(void* const* d_in, const int* in_sizes, int n_in,
                              void* d_out, int out_size, void* d_ws, size_t ws_size,
                              hipStream_t stream) {
    const float* stim         = (const float*)d_in[0];  // (B,E,3)
    const float* params       = (const float*)d_in[1];  // (B,12)
    const float* axon_contrib = (const float*)d_in[2];  // (P,L,3)
    const float* d2_el        = (const float*)d_in[3];  // (P,L,E)
    float* out = (float*)d_out;                         // (B,P) = 20000 floats

    axon_fused<<<P_TOT, 256, 0, stream>>>(stim, params, axon_contrib, d2_el, out);
}